// Round 1
// baseline (734.950 us; speedup 1.0000x reference)
//
#include <hip/hip_runtime.h>
#include <hip/hip_bf16.h>

#define BATCH 4096
#define NGENE 3000
#define HID   6
#define GPT   30
#define T0N   500
#define T1N   50
#define KP    3008    // K padded (47 * 64)
#define MROWS 4608    // 3000 (V0 rows) + 1530 (dg mid/root) + 78 pad
#define OUTW  3857
#define BNEPS 1e-5f
#define NKT   47      // K-tiles of 64
#define LDSU  24576   // ushorts per LDS buffer (48 KB): A 16384 + B 8192

typedef __attribute__((ext_vector_type(8))) __bf16 bf16x8;
typedef __attribute__((ext_vector_type(4))) float f32x4;
typedef __attribute__((ext_vector_type(8))) unsigned short ushort8;

__device__ __forceinline__ unsigned short f2bf(float f) {
  unsigned int u = __builtin_bit_cast(unsigned int, f);
  u = (u + 0x7fffu + ((u >> 16) & 1u)) >> 16;
  return (unsigned short)u;
}

__device__ __forceinline__ void gload_lds16(const void* g, void* l) {
  __builtin_amdgcn_global_load_lds(
      (const __attribute__((address_space(1))) unsigned int*)g,
      (__attribute__((address_space(3))) unsigned int*)l, 16, 0, 0);
}

// ---- cast cell fp32 -> bf16, [4096][KP], zero pad ----
__global__ void cast_cell(const float* __restrict__ x, ushort8* __restrict__ y) {
  int idx = blockIdx.x * 256 + threadIdx.x;     // < 4096*376
  int r = idx / 376, c8 = idx - r * 376;
  int c = c8 * 8;
  ushort8 o = (ushort8)0;
  if (c < NGENE) {
    const float4* p = (const float4*)(x + (size_t)r * NGENE + c);
    float4 a = p[0], b = p[1];
    o[0] = f2bf(a.x); o[1] = f2bf(a.y); o[2] = f2bf(a.z); o[3] = f2bf(a.w);
    o[4] = f2bf(b.x); o[5] = f2bf(b.y); o[6] = f2bf(b.z); o[7] = f2bf(b.w);
  }
  y[idx] = o;
}

// ---- V0[t*6+h][n] = sum_g W0[t,h,g]*Wdg[t,g,n], written bf16 into abuf ----
__global__ void v0_build(const float* __restrict__ Wdg, const float* __restrict__ W0,
                         unsigned short* __restrict__ abuf) {
  int n = blockIdx.x * 256 + threadIdx.x;   // gridDim.x=12 -> 3072
  int t = blockIdx.y;
  if (n >= KP) return;
  bool valid = n < NGENE;
  float x[GPT];
#pragma unroll
  for (int g = 0; g < GPT; ++g)
    x[g] = valid ? Wdg[((size_t)(t * GPT + g)) * NGENE + n] : 0.f;
#pragma unroll
  for (int h = 0; h < HID; ++h) {
    const float* w = W0 + (t * HID + h) * GPT;  // wave-uniform
    float s = 0.f;
#pragma unroll
    for (int g = 0; g < GPT; ++g) s += x[g] * w[g];
    abuf[((size_t)(t * HID + h)) * KP + n] = valid ? f2bf(s) : (unsigned short)0;
  }
}

// ---- cast Wdg rows 15000..16529 -> abuf rows 3000..4529; zero rows 4530..4607 ----
__global__ void cast_wdg_mid(const float* __restrict__ w, ushort8* __restrict__ y) {
  int idx = blockIdx.x * 256 + threadIdx.x;   // < 1608*376
  if (idx >= 1608 * 376) return;
  int r = idx / 376, c8 = idx - r * 376;
  int c = c8 * 8;
  ushort8 o = (ushort8)0;
  if (r < 1530 && c < NGENE) {
    const float4* p = (const float4*)(w + (size_t)(15000 + r) * NGENE + c);
    float4 a = p[0], b = p[1];
    o[0] = f2bf(a.x); o[1] = f2bf(a.y); o[2] = f2bf(a.z); o[3] = f2bf(a.w);
    o[4] = f2bf(b.x); o[5] = f2bf(b.y); o[6] = f2bf(b.z); o[7] = f2bf(b.w);
  }
  y[(size_t)(3000 + r) * 376 + c8] = o;
}

// ---- bias: rows<3000 -> b0 + W0·bdg ; 3000..4529 -> bdg[15000+..] ; else 0 ----
__global__ void build_bias(const float* __restrict__ bdg, const float* __restrict__ W0,
                           const float* __restrict__ b0, float* __restrict__ bias) {
  int idx = blockIdx.x * 256 + threadIdx.x;
  if (idx >= MROWS) return;
  float v = 0.f;
  if (idx < 3000) {
    int t = idx / HID;
    float s = b0[idx];
#pragma unroll
    for (int g = 0; g < GPT; ++g) s += W0[idx * GPT + g] * bdg[t * GPT + g];
    v = s;
  } else if (idx < 4530) {
    v = bdg[15000 + idx - 3000];
  }
  bias[idx] = v;
}

// ---- GEMM: C[m][b] = A[m,:]·cell[b,:] + bias[m]; tanh for m<3000.
// 256x128 tile, BK=64, 8 waves (4M x 2N, 64x64 per wave), 3-deep LDS pipeline,
// counted vmcnt, raw barriers, XOR k-swizzle (pre-swizzled global source),
// setprio around MFMA clusters, fused layer-0 column stats via atomics. ----
__global__ __launch_bounds__(512, 2) void gemm_fused(
    const unsigned short* __restrict__ A,    // [MROWS][KP] bf16
    const unsigned short* __restrict__ Bt,   // [BATCH][KP] bf16
    const float* __restrict__ bias,
    float* __restrict__ C,                   // [MROWS][BATCH] fp32
    float* __restrict__ st) {                // layer-0 stats accumulators
  extern __shared__ unsigned short smem[];   // 3 * 24576 ushorts = 144 KB
  const int tid  = threadIdx.x;
  const int wave = tid >> 6, lane = tid & 63;
  const int wm = wave >> 1, wn = wave & 1;        // 4M x 2N waves
  const int quad = lane >> 4, fr = lane & 15, fs = lane & 7;

  // XCD-bijective block swizzle (576 % 8 == 0)
  const int bid = blockIdx.x;
  const int wg  = (bid & 7) * 72 + (bid >> 3);
  const int m0 = (wg >> 5) * 256;                 // 18 m-tiles
  const int n0 = (wg & 31) * 128;                 // 32 n-tiles

  // staging source pointers (global pre-swizzled so LDS dest stays linear)
  const int s0 = tid, s1 = tid + 512;
  const int r0 = s0 >> 3, k0 = s0 & 7;
  const int r1 = s1 >> 3, k1 = s1 & 7;
  const unsigned short* gA00 = A  + (size_t)(m0 + r0) * KP + ((k0 ^ (r0 & 7)) << 3);
  const unsigned short* gA01 = A  + (size_t)(m0 + r1) * KP + ((k1 ^ (r1 & 7)) << 3);
  const unsigned short* gA10 = gA00 + (size_t)128 * KP;
  const unsigned short* gA11 = gA01 + (size_t)128 * KP;
  const unsigned short* gB00 = Bt + (size_t)(n0 + r0) * KP + ((k0 ^ (r0 & 7)) << 3);
  const unsigned short* gB01 = Bt + (size_t)(n0 + r1) * KP + ((k1 ^ (r1 & 7)) << 3);
  const int d0 = (wave * 64) * 8;          // wave-uniform LDS dst (ushorts), inst 0
  const int d1 = (512 + wave * 64) * 8;    // inst 1

  f32x4 acc[4][4] = {};

  // prologue: stage K-tiles 0 -> buf0, 1 -> buf1 (6 loads each)
#pragma unroll
  for (int t = 0; t < 2; ++t) {
    unsigned short* base = smem + t * LDSU;
    const int ko = t * 64;
    gload_lds16(gA00 + ko, base + d0);
    gload_lds16(gA01 + ko, base + d1);
    gload_lds16(gA10 + ko, base + 8192 + d0);
    gload_lds16(gA11 + ko, base + 8192 + d1);
    gload_lds16(gB00 + ko, base + 16384 + d0);
    gload_lds16(gB01 + ko, base + 16384 + d1);
  }
  asm volatile("s_waitcnt vmcnt(6)" ::: "memory");   // tile 0 landed; tile 1 in flight
  __builtin_amdgcn_s_barrier();

  // ds_read fragment addressing (ushort units); swizzled k-slot = (k16 ^ (row&7))
  const int arow0 = (wm * 64 + fr) * 64;
  const int brow0 = (wn * 64 + fr) * 64;
  const int ksw0 = ((quad ^ fs) << 3);
  const int ksw1 = ksw0 ^ 32;                        // ((4+quad)^fs)<<3

  int cur = 0;
  for (int t = 0; t < NKT; ++t) {
    const unsigned short* Ab = smem + cur * LDSU;
    const unsigned short* Bb = Ab + 16384;
    int stg = cur + 2; if (stg >= 3) stg -= 3;
    unsigned short* sb = smem + stg * LDSU;
    const bool pf = t < NKT - 2;
    const int ko = (t + 2) * 64;

    bf16x8 a0[2][2], a1[2][2], b0[2][2], b1[2][2];
    // ---------- phase 1: read A-low + B-low, stage chunk A0(t+2) ----------
#pragma unroll
    for (int f = 0; f < 2; ++f) {
      a0[f][0] = *(const bf16x8*)(Ab + arow0 + f * 1024 + ksw0);
      a0[f][1] = *(const bf16x8*)(Ab + arow0 + f * 1024 + ksw1);
      b0[f][0] = *(const bf16x8*)(Bb + brow0 + f * 1024 + ksw0);
      b0[f][1] = *(const bf16x8*)(Bb + brow0 + f * 1024 + ksw1);
    }
    if (pf) {
      gload_lds16(gA00 + ko, sb + d0);
      gload_lds16(gA01 + ko, sb + d1);
    }
    __builtin_amdgcn_s_barrier();
    asm volatile("s_waitcnt lgkmcnt(0)" ::: "memory");
    __builtin_amdgcn_s_setprio(1);
#pragma unroll
    for (int i = 0; i < 2; ++i)
#pragma unroll
      for (int j = 0; j < 2; ++j)
#pragma unroll
        for (int k = 0; k < 2; ++k)
          acc[i][j] = __builtin_amdgcn_mfma_f32_16x16x32_bf16(a0[i][k], b0[j][k], acc[i][j], 0, 0, 0);
    __builtin_amdgcn_s_setprio(0);
    __builtin_amdgcn_s_barrier();
    // ---------- phase 2: read B-high, stage chunk A1(t+2) ----------
#pragma unroll
    for (int f = 0; f < 2; ++f) {
      b1[f][0] = *(const bf16x8*)(Bb + brow0 + (f + 2) * 1024 + ksw0);
      b1[f][1] = *(const bf16x8*)(Bb + brow0 + (f + 2) * 1024 + ksw1);
    }
    if (pf) {
      gload_lds16(gA10 + ko, sb + 8192 + d0);
      gload_lds16(gA11 + ko, sb + 8192 + d1);
    }
    __builtin_amdgcn_s_barrier();
    asm volatile("s_waitcnt lgkmcnt(0)" ::: "memory");
    __builtin_amdgcn_s_setprio(1);
#pragma unroll
    for (int i = 0; i < 2; ++i)
#pragma unroll
      for (int j = 0; j < 2; ++j)
#pragma unroll
        for (int k = 0; k < 2; ++k)
          acc[i][2 + j] = __builtin_amdgcn_mfma_f32_16x16x32_bf16(a0[i][k], b1[j][k], acc[i][2 + j], 0, 0, 0);
    __builtin_amdgcn_s_setprio(0);
    __builtin_amdgcn_s_barrier();
    // ---------- phase 3: read A-high, stage chunk B(t+2) ----------
#pragma unroll
    for (int f = 0; f < 2; ++f) {
      a1[f][0] = *(const bf16x8*)(Ab + arow0 + (f + 2) * 1024 + ksw0);
      a1[f][1] = *(const bf16x8*)(Ab + arow0 + (f + 2) * 1024 + ksw1);
    }
    if (pf) {
      gload_lds16(gB00 + ko, sb + 16384 + d0);
      gload_lds16(gB01 + ko, sb + 16384 + d1);
    }
    __builtin_amdgcn_s_barrier();
    asm volatile("s_waitcnt lgkmcnt(0)" ::: "memory");
    __builtin_amdgcn_s_setprio(1);
#pragma unroll
    for (int i = 0; i < 2; ++i)
#pragma unroll
      for (int j = 0; j < 2; ++j)
#pragma unroll
        for (int k = 0; k < 2; ++k)
          acc[2 + i][2 + j] = __builtin_amdgcn_mfma_f32_16x16x32_bf16(a1[i][k], b1[j][k], acc[2 + i][2 + j], 0, 0, 0);
    __builtin_amdgcn_s_setprio(0);
    __builtin_amdgcn_s_barrier();
    // ---------- phase 4: MFMA A-high x B-low, then counted vmcnt ----------
    __builtin_amdgcn_s_setprio(1);
#pragma unroll
    for (int i = 0; i < 2; ++i)
#pragma unroll
      for (int j = 0; j < 2; ++j)
#pragma unroll
        for (int k = 0; k < 2; ++k)
          acc[2 + i][j] = __builtin_amdgcn_mfma_f32_16x16x32_bf16(a1[i][k], b0[j][k], acc[2 + i][j], 0, 0, 0);
    __builtin_amdgcn_s_setprio(0);
    if (pf) {
      asm volatile("s_waitcnt vmcnt(6)" ::: "memory");  // t+1's 6 retired; t+2's stay in flight
    } else {
      asm volatile("s_waitcnt vmcnt(0)" ::: "memory");  // drain tail
    }
    __builtin_amdgcn_s_barrier();
    cur += 1; if (cur == 3) cur = 0;
  }

  // ---------- epilogue: bias + tanh + C write + fused layer-0 column stats ----------
  const int mbase = m0 + wm * 64 + quad * 4;
  const int nbase = n0 + wn * 64 + fr;
#pragma unroll
  for (int i = 0; i < 4; ++i) {
#pragma unroll
    for (int r = 0; r < 4; ++r) {
      const int m = mbase + i * 16 + r;
      const float bia = bias[m];
      const bool act = m < 3000;   // uniform within each quad group
      float s = 0.f, q = 0.f;
#pragma unroll
      for (int j = 0; j < 4; ++j) {
        float v = acc[i][j][r] + bia;
        if (act) v = tanhf(v);
        C[(size_t)m * BATCH + nbase + j * 16] = v;
        s += v; q += v * v;
      }
      if (act) {
#pragma unroll
        for (int off = 1; off < 16; off <<= 1) {
          s += __shfl_xor(s, off);
          q += __shfl_xor(q, off);
        }
        if (fr == 0) {
          atomicAdd(&st[2 * m], s);
          atomicAdd(&st[2 * m + 1], q);
        }
      }
    }
  }
}

// ---- BN finalize ----
__global__ void bnfin(const float* __restrict__ st, const float* __restrict__ gam,
                      const float* __restrict__ bet, float* __restrict__ ss, int ncols) {
  int c = blockIdx.x * 256 + threadIdx.x;
  if (c >= ncols) return;
  float m = st[2 * c] * (1.f / BATCH);
  float v = st[2 * c + 1] * (1.f / BATCH) - m * m;
  float sc = gam[c] * rsqrtf(v + BNEPS);
  ss[2 * c] = sc;
  ss[2 * c + 1] = bet[c] - m * sc;
}

// ---- normalize zT + transpose-emit into out[b][outoff + c] ----
__global__ void norm_emit(const float* __restrict__ zT, const float* __restrict__ ss,
                          float* __restrict__ out, int ncols, int outoff) {
  __shared__ float tile[64][65];
  int lane = threadIdx.x & 63, w = threadIdx.x >> 6;
  int c0 = blockIdx.x * 64, b0 = blockIdx.y * 64;
#pragma unroll
  for (int i = 0; i < 16; ++i) {
    int cc = w * 16 + i, c = c0 + cc;
    float n = 0.f;
    if (c < ncols)
      n = zT[(size_t)c * BATCH + b0 + lane] * ss[2 * c] + ss[2 * c + 1];
    tile[cc][lane] = n;
  }
  __syncthreads();
  int c = c0 + lane;
  if (c < ncols) {
#pragma unroll
    for (int i = 0; i < 16; ++i) {
      int rr = w * 16 + i;
      out[(size_t)(b0 + rr) * OUTW + outoff + c] = tile[lane][rr];
    }
  }
}

// ---- aux head ----
__global__ void aux_head(const float* __restrict__ zT, const float* __restrict__ ss,
                         const float* __restrict__ aw, const float* __restrict__ ab,
                         const float* __restrict__ av, const float* __restrict__ ac,
                         float* __restrict__ out, int nterm, int auxoff) {
  int lane = threadIdx.x & 63, tg = threadIdx.x >> 6;
  int t = blockIdx.x * 4 + tg;
  if (t >= nterm) return;
  int b = blockIdx.y * 64 + lane;
  float s = ab[t];
#pragma unroll
  for (int h = 0; h < HID; ++h) {
    int c = t * HID + h;
    float n = zT[(size_t)c * BATCH + b] * ss[2 * c] + ss[2 * c + 1];
    s += n * aw[c];
  }
  out[(size_t)b * OUTW + auxoff + t] = tanhf(s) * av[t] + ac[t];
}

// ---- layer 1: z1T from normalized z0T children + raw dg mid; fused stats ----
__global__ void layer1_zT(const float* __restrict__ C, const float* __restrict__ ss0,
                          const float* __restrict__ W1, const float* __restrict__ b1,
                          float* __restrict__ z1T, float* __restrict__ st) {
  int lane = threadIdx.x & 63, tg = threadIdx.x >> 6;
  int t = blockIdx.x * 4 + tg;
  if (t >= T1N) return;
  int b = blockIdx.y * 64 + lane;
  const float* z0T = C;
  const float* dgm = C + (size_t)3000 * BATCH;
  float x[90];
#pragma unroll
  for (int j = 0; j < 60; ++j) {
    int c = t * 60 + j;
    x[j] = z0T[(size_t)c * BATCH + b] * ss0[2 * c] + ss0[2 * c + 1];
  }
#pragma unroll
  for (int g = 0; g < GPT; ++g)
    x[60 + g] = dgm[(size_t)(t * GPT + g) * BATCH + b];
#pragma unroll
  for (int h = 0; h < HID; ++h) {
    int c = t * HID + h;
    const float* w = W1 + c * 90;
    float s = b1[c];
#pragma unroll
    for (int i = 0; i < 90; ++i) s += x[i] * w[i];
    float z = tanhf(s);
    z1T[(size_t)c * BATCH + b] = z;
    float s1 = z, s2 = z * z;
#pragma unroll
    for (int off = 32; off > 0; off >>= 1) {
      s1 += __shfl_down(s1, off);
      s2 += __shfl_down(s2, off);
    }
    if (lane == 0) {
      atomicAdd(&st[2 * c], s1);
      atomicAdd(&st[2 * c + 1], s2);
    }
  }
}

// ---- root ----
__global__ void root_zT(const float* __restrict__ C, const float* __restrict__ z1T,
                        const float* __restrict__ ss1, const float* __restrict__ W2,
                        const float* __restrict__ b2, float* __restrict__ z2T,
                        float* __restrict__ st) {
  int b = blockIdx.x * 256 + threadIdx.x;
  int lane = threadIdx.x & 63;
  const float* dgr = C + (size_t)4500 * BATCH;
  float s[HID];
#pragma unroll
  for (int h = 0; h < HID; ++h) s[h] = b2[h];
  for (int c = 0; c < 300; ++c) {
    float n = z1T[(size_t)c * BATCH + b] * ss1[2 * c] + ss1[2 * c + 1];
#pragma unroll
    for (int h = 0; h < HID; ++h) s[h] += n * W2[h * 330 + c];
  }
#pragma unroll
  for (int g = 0; g < GPT; ++g) {
    float d = dgr[(size_t)g * BATCH + b];
#pragma unroll
    for (int h = 0; h < HID; ++h) s[h] += d * W2[h * 330 + 300 + g];
  }
#pragma unroll
  for (int h = 0; h < HID; ++h) {
    float z = tanhf(s[h]);
    z2T[(size_t)h * BATCH + b] = z;
    float s1 = z, s2 = z * z;
#pragma unroll
    for (int off = 32; off > 0; off >>= 1) {
      s1 += __shfl_down(s1, off);
      s2 += __shfl_down(s2, off);
    }
    if (lane == 0) {
      atomicAdd(&st[2 * h], s1);
      atomicAdd(&st[2 * h + 1], s2);
    }
  }
}

__global__ void root_emit(const float* __restrict__ z2T, const float* __restrict__ ss2,
                          const float* __restrict__ aw2, const float* __restrict__ ab2,
                          const float* __restrict__ av2, const float* __restrict__ ac2,
                          float* __restrict__ out) {
  int b = blockIdx.x * 256 + threadIdx.x;
  float s = ab2[0];
#pragma unroll
  for (int h = 0; h < HID; ++h) {
    float n = z2T[(size_t)h * BATCH + b] * ss2[2 * h] + ss2[2 * h + 1];
    out[(size_t)b * OUTW + 3851 + h] = n;
    s += n * aw2[h];
  }
  out[(size_t)b * OUTW + 550] = tanhf(s) * av2[0] + ac2[0];
}

extern "C" void kernel_launch(void* const* d_in, const int* in_sizes, int n_in,
                              void* d_out, int out_size, void* d_ws, size_t ws_size,
                              hipStream_t stream) {
  (void)in_sizes; (void)n_in; (void)out_size; (void)ws_size;
  const float* cell = (const float*)d_in[0];
  const float* Wdg  = (const float*)d_in[1];
  const float* bdg  = (const float*)d_in[2];
  const float* W0   = (const float*)d_in[3];
  const float* b0   = (const float*)d_in[4];
  const float* gam0 = (const float*)d_in[5];
  const float* bet0 = (const float*)d_in[6];
  const float* aw0  = (const float*)d_in[7];
  const float* ab0  = (const float*)d_in[8];
  const float* av0  = (const float*)d_in[9];
  const float* ac0  = (const float*)d_in[10];
  const float* W1   = (const float*)d_in[11];
  const float* b1   = (const float*)d_in[12];
  const float* gam1 = (const float*)d_in[13];
  const float* bet1 = (const float*)d_in[14];
  const float* aw1  = (const float*)d_in[15];
  const float* ab1  = (const float*)d_in[16];
  const float* av1  = (const float*)d_in[17];
  const float* ac1  = (const float*)d_in[18];
  const float* W2   = (const float*)d_in[19];
  const float* b2   = (const float*)d_in[20];
  const float* gam2 = (const float*)d_in[21];
  const float* bet2 = (const float*)d_in[22];
  const float* aw2  = (const float*)d_in[23];
  const float* ab2  = (const float*)d_in[24];
  const float* av2  = (const float*)d_in[25];
  const float* ac2  = (const float*)d_in[26];
  float* out = (float*)d_out;

  char* ws = (char*)d_ws;
  unsigned short* cellb = (unsigned short*)(ws);               // 24,641,536
  unsigned short* abuf  = (unsigned short*)(ws + 24641536);    // 27,721,728
  float*          C     = (float*)(ws + 52363264);             // 75,497,472
  float*          z1T   = (float*)(ws + 127860736);            // 4,915,200
  float*          z2T   = (float*)(ws + 132775936);            // 98,304
  float*          st    = (float*)(ws + 132874240);            // 26,448 (pad 32768)
  float*          ssb   = (float*)(ws + 132907008);            // 26,448 (pad 32768)
  float*          bias  = (float*)(ws + 132939776);            // 18,432
  float* st0 = st,  *st1 = st + 2 * 3000,  *st2 = st + 2 * 3300;
  float* ss0 = ssb, *ss1 = ssb + 2 * 3000, *ss2 = ssb + 2 * 3300;

  static int s_attr = 0;
  if (!s_attr) {
    hipFuncSetAttribute(reinterpret_cast<const void*>(gemm_fused),
                        hipFuncAttributeMaxDynamicSharedMemorySize, 147456);
    s_attr = 1;
  }

  hipMemsetAsync(st, 0, 32768, stream);   // layer0/layer1/root stat accumulators
  cast_cell<<<6016, 256, 0, stream>>>(cell, (ushort8*)cellb);
  v0_build<<<dim3(12, T0N), 256, 0, stream>>>(Wdg, W0, abuf);
  cast_wdg_mid<<<2362, 256, 0, stream>>>(Wdg, (ushort8*)abuf);
  build_bias<<<18, 256, 0, stream>>>(bdg, W0, b0, bias);

  gemm_fused<<<576, 512, 147456, stream>>>(abuf, cellb, bias, C, st0);

  bnfin<<<12, 256, 0, stream>>>(st0, gam0, bet0, ss0, 3000);
  norm_emit<<<dim3(47, 64), 256, 0, stream>>>(C, ss0, out, 3000, 551);
  aux_head<<<dim3(125, 64), 256, 0, stream>>>(C, ss0, aw0, ab0, av0, ac0, out, 500, 0);

  layer1_zT<<<dim3(13, 64), 256, 0, stream>>>(C, ss0, W1, b1, z1T, st1);
  bnfin<<<2, 256, 0, stream>>>(st1, gam1, bet1, ss1, 300);
  norm_emit<<<dim3(5, 64), 256, 0, stream>>>(z1T, ss1, out, 300, 3551);
  aux_head<<<dim3(13, 64), 256, 0, stream>>>(z1T, ss1, aw1, ab1, av1, ac1, out, 50, 500);

  root_zT<<<16, 256, 0, stream>>>(C, z1T, ss1, W2, b2, z2T, st2);
  bnfin<<<1, 256, 0, stream>>>(st2, gam2, bet2, ss2, 6);
  root_emit<<<16, 256, 0, stream>>>(z2T, ss2, aw2, ab2, av2, ac2, out);
}

// Round 3
// 678.531 us; speedup vs baseline: 1.0831x; 1.0831x over previous
//
#include <hip/hip_runtime.h>
#include <hip/hip_bf16.h>

#define BATCH 4096
#define NGENE 3000
#define HID   6
#define GPT   30
#define T0N   500
#define T1N   50
#define KP    3008    // K padded (94 * 32)
#define MROWS 4608    // 3000 (V0 rows) + 1530 (dg mid/root) + 78 pad
#define OUTW  3857
#define BNEPS 1e-5f
#define NIT   94      // K-steps of 32
#define BUFU  12288   // ushorts per LDS buffer: A 256x32 (8192) + B 128x32 (4096)

typedef __attribute__((ext_vector_type(8))) __bf16 bf16x8;
typedef __attribute__((ext_vector_type(4))) float f32x4;
typedef __attribute__((ext_vector_type(8))) unsigned short ushort8;

__device__ __forceinline__ unsigned short f2bf(float f) {
  unsigned int u = __builtin_bit_cast(unsigned int, f);
  u = (u + 0x7fffu + ((u >> 16) & 1u)) >> 16;
  return (unsigned short)u;
}

__device__ __forceinline__ void gload_lds16(const void* g, void* l) {
  __builtin_amdgcn_global_load_lds(
      (const __attribute__((address_space(1))) unsigned int*)g,
      (__attribute__((address_space(3))) unsigned int*)l, 16, 0, 0);
}

// ---- merged prep: cast cell -> bf16 | cast Wdg mid rows + zero tail | build bias ----
__global__ void prep(const float* __restrict__ cell, const float* __restrict__ Wdg,
                     const float* __restrict__ bdg, const float* __restrict__ W0,
                     const float* __restrict__ b0,
                     ushort8* __restrict__ cellb, ushort8* __restrict__ abuf8,
                     float* __restrict__ bias) {
  int blk = blockIdx.x;
  if (blk < 6016) {
    // cast cell fp32 -> bf16, [4096][KP], zero pad
    int idx = blk * 256 + threadIdx.x;          // < 4096*376 exactly
    int r = idx / 376, c8 = idx - r * 376;
    int c = c8 * 8;
    ushort8 o = (ushort8)0;
    if (c < NGENE) {
      const float4* p = (const float4*)(cell + (size_t)r * NGENE + c);
      float4 a = p[0], b = p[1];
      o[0] = f2bf(a.x); o[1] = f2bf(a.y); o[2] = f2bf(a.z); o[3] = f2bf(a.w);
      o[4] = f2bf(b.x); o[5] = f2bf(b.y); o[6] = f2bf(b.z); o[7] = f2bf(b.w);
    }
    cellb[idx] = o;
  } else if (blk < 8378) {
    // cast Wdg rows 15000..16529 -> abuf rows 3000..4529; zero rows 4530..4607
    int idx = (blk - 6016) * 256 + threadIdx.x;
    if (idx >= 1608 * 376) return;
    int r = idx / 376, c8 = idx - r * 376;
    int c = c8 * 8;
    ushort8 o = (ushort8)0;
    if (r < 1530 && c < NGENE) {
      const float4* p = (const float4*)(Wdg + (size_t)(15000 + r) * NGENE + c);
      float4 a = p[0], b = p[1];
      o[0] = f2bf(a.x); o[1] = f2bf(a.y); o[2] = f2bf(a.z); o[3] = f2bf(a.w);
      o[4] = f2bf(b.x); o[5] = f2bf(b.y); o[6] = f2bf(b.z); o[7] = f2bf(b.w);
    }
    abuf8[(size_t)(3000 + r) * 376 + c8] = o;
  } else {
    // bias: rows<3000 -> b0 + W0·bdg ; 3000..4529 -> bdg[15000+..] ; else 0
    int idx = (blk - 8378) * 256 + threadIdx.x;
    if (idx >= MROWS) return;
    float v = 0.f;
    if (idx < 3000) {
      int t = idx / HID;
      float s = b0[idx];
#pragma unroll
      for (int g = 0; g < GPT; ++g) s += W0[idx * GPT + g] * bdg[t * GPT + g];
      v = s;
    } else if (idx < 4530) {
      v = bdg[15000 + idx - 3000];
    }
    bias[idx] = v;
  }
}

// ---- V0[t*6+h][n] = sum_g W0[t,h,g]*Wdg[t,g,n], written bf16 into abuf ----
__global__ void v0_build(const float* __restrict__ Wdg, const float* __restrict__ W0,
                         unsigned short* __restrict__ abuf) {
  int n = blockIdx.x * 256 + threadIdx.x;   // gridDim.x=12 -> 3072
  int t = blockIdx.y;
  if (n >= KP) return;
  bool valid = n < NGENE;
  float x[GPT];
#pragma unroll
  for (int g = 0; g < GPT; ++g)
    x[g] = valid ? Wdg[((size_t)(t * GPT + g)) * NGENE + n] : 0.f;
#pragma unroll
  for (int h = 0; h < HID; ++h) {
    const float* w = W0 + (t * HID + h) * GPT;  // wave-uniform
    float s = 0.f;
#pragma unroll
    for (int g = 0; g < GPT; ++g) s += x[g] * w[g];
    abuf[((size_t)(t * HID + h)) * KP + n] = valid ? f2bf(s) : (unsigned short)0;
  }
}

// ---- GEMM: C[m][b] = A[m,:]·cell[b,:] + bias[m]; tanh for m<3000; fused L0 stats.
// 256x128 tile, BK=32, 512 thr (8 waves 4Mx2N, wave=64x64), triple-buffered 72KB LDS
// -> 2 blocks/CU, counted vmcnt(3) (2-iter prefetch depth, never drains in steady
// state), one raw s_barrier/iter, XOR k-swizzle via pre-swizzled global source
// (0 bank conflicts), setprio around the 16-MFMA cluster. ----
__global__ __launch_bounds__(512, 2) void gemm_fused(
    const unsigned short* __restrict__ A,    // [MROWS][KP] bf16
    const unsigned short* __restrict__ Bt,   // [BATCH][KP] bf16
    const float* __restrict__ bias,
    float* __restrict__ C,                   // [MROWS][BATCH] fp32
    float* __restrict__ st) {                // layer-0 stats accumulators
  extern __shared__ unsigned short smem[];   // 3 * 12288 ushorts = 73728 B
  const int tid  = threadIdx.x;
  const int wave = tid >> 6, lane = tid & 63;
  const int wm = wave >> 1, wn = wave & 1;        // 4M x 2N waves, 64x64 each
  const int quad = lane >> 4, fr = lane & 15;

  // XCD-bijective block swizzle (576 % 8 == 0)
  const int bid = blockIdx.x;
  const int wg  = (bid & 7) * 72 + (bid >> 3);
  const int m0 = (wg >> 5) * 256;                 // 18 m-tiles
  const int n0 = (wg & 31) * 128;                 // 32 n-tiles

  // staging: LDS dest linear, global source pre-swizzled (slot ^= (row>>2)&3)
  const int r   = tid >> 2;
  const int ssw = (tid & 3) ^ ((r >> 2) & 3);
  const unsigned short* gA0 = A  + (size_t)(m0 + r) * KP + ssw * 8;
  const unsigned short* gA1 = A  + (size_t)(m0 + 128 + r) * KP + ssw * 8;
  const unsigned short* gB0 = Bt + (size_t)(n0 + r) * KP + ssw * 8;
  const int dA0 = wave * 512;              // wave-uniform LDS dst (ushorts)
  const int dA1 = 4096 + wave * 512;
  const int dB0 = 8192 + wave * 512;

  f32x4 acc[4][4] = {};

  // prologue: stage K-steps 0 -> buf0, 1 -> buf1 (3 loads each)
#pragma unroll
  for (int t = 0; t < 2; ++t) {
    unsigned short* base = smem + t * BUFU;
    gload_lds16(gA0 + t * 32, base + dA0);
    gload_lds16(gA1 + t * 32, base + dA1);
    gload_lds16(gB0 + t * 32, base + dB0);
  }
  asm volatile("s_waitcnt vmcnt(3)" ::: "memory");  // step 0 landed; step 1 in flight
  __builtin_amdgcn_s_barrier();

  // ds_read fragment addressing: swizzled 16B slot = quad ^ ((fr>>2)&3)
  const int swz  = (quad ^ ((fr >> 2) & 3)) << 3;
  const int aoff = (wm * 64 + fr) * 32 + swz;
  const int boff = 8192 + (wn * 64 + fr) * 32 + swz;

  int cur = 0;
  for (int t = 0; t < NIT; ++t) {
    if (t < NIT - 2) {   // stage step t+2 into the buffer freed at iter t-1
      unsigned short* sb = smem + ((cur >= 1) ? cur - 1 : 2) * BUFU;
      const int ko = (t + 2) * 32;
      gload_lds16(gA0 + ko, sb + dA0);
      gload_lds16(gA1 + ko, sb + dA1);
      gload_lds16(gB0 + ko, sb + dB0);
    }
    const unsigned short* buf = smem + cur * BUFU;
    bf16x8 af[4], bf[4];
#pragma unroll
    for (int i = 0; i < 4; ++i) af[i] = *(const bf16x8*)(buf + aoff + i * 512);
#pragma unroll
    for (int j = 0; j < 4; ++j) bf[j] = *(const bf16x8*)(buf + boff + j * 512);
    __builtin_amdgcn_s_setprio(1);
#pragma unroll
    for (int i = 0; i < 4; ++i)
#pragma unroll
      for (int j = 0; j < 4; ++j)
        acc[i][j] = __builtin_amdgcn_mfma_f32_16x16x32_bf16(af[i], bf[j], acc[i][j], 0, 0, 0);
    __builtin_amdgcn_s_setprio(0);
    asm volatile("s_waitcnt lgkmcnt(0)" ::: "memory");
    if (t < NIT - 2) asm volatile("s_waitcnt vmcnt(3)" ::: "memory");  // t+1 landed, t+2 in flight
    else             asm volatile("s_waitcnt vmcnt(0)" ::: "memory");  // tail drain
    __builtin_amdgcn_s_barrier();
    cur = (cur == 2) ? 0 : cur + 1;
  }

  // ---------- epilogue: bias + tanh + C write + fused layer-0 column stats ----------
  const int mbase = m0 + wm * 64 + quad * 4;
  const int nbase = n0 + wn * 64 + fr;
#pragma unroll
  for (int i = 0; i < 4; ++i) {
#pragma unroll
    for (int rr = 0; rr < 4; ++rr) {
      const int m = mbase + i * 16 + rr;
      const float bia = bias[m];
      const bool act = m < 3000;
      float s = 0.f, q = 0.f;
#pragma unroll
      for (int j = 0; j < 4; ++j) {
        float v = acc[i][j][rr] + bia;
        if (act) v = tanhf(v);
        C[(size_t)m * BATCH + nbase + j * 16] = v;
        s += v; q += v * v;
      }
      if (act) {
#pragma unroll
        for (int off = 1; off < 16; off <<= 1) {
          s += __shfl_xor(s, off);
          q += __shfl_xor(q, off);
        }
        if (fr == 0) {
          atomicAdd(&st[2 * m], s);
          atomicAdd(&st[2 * m + 1], q);
        }
      }
    }
  }
}

// ---- BN finalize ----
__global__ void bnfin(const float* __restrict__ st, const float* __restrict__ gam,
                      const float* __restrict__ bet, float* __restrict__ ss, int ncols) {
  int c = blockIdx.x * 256 + threadIdx.x;
  if (c >= ncols) return;
  float m = st[2 * c] * (1.f / BATCH);
  float v = st[2 * c + 1] * (1.f / BATCH) - m * m;
  float sc = gam[c] * rsqrtf(v + BNEPS);
  ss[2 * c] = sc;
  ss[2 * c + 1] = bet[c] - m * sc;
}

// ---- normalize zT + transpose-emit + fused aux head (66-col tiles = 11 whole terms) ----
__global__ void norm_emit_aux(const float* __restrict__ zT, const float* __restrict__ ss,
                              const float* __restrict__ aw, const float* __restrict__ ab,
                              const float* __restrict__ av, const float* __restrict__ ac,
                              float* __restrict__ out, int ncols, int outoff,
                              int auxoff, int nterm) {
  __shared__ float tile[66][65];
  int lane = threadIdx.x & 63, w = threadIdx.x >> 6;
  int c0 = blockIdx.x * 66, b0 = blockIdx.y * 64;
  for (int cc = w; cc < 66; cc += 4) {
    int c = c0 + cc;
    float n = 0.f;
    if (c < ncols)
      n = zT[(size_t)c * BATCH + b0 + lane] * ss[2 * c] + ss[2 * c + 1];
    tile[cc][lane] = n;
  }
  __syncthreads();
  // emit normalized values (transposed, coalesced over cols)
  for (int cl = lane; cl < 66; cl += 64) {
    int c = c0 + cl;
    if (c < ncols) {
#pragma unroll
      for (int i = 0; i < 16; ++i) {
        int rr = w * 16 + i;
        out[(size_t)(b0 + rr) * OUTW + outoff + c] = tile[cl][rr];
      }
    }
  }
  // aux heads for the 11 whole terms in this tile
  int t0 = c0 / 6;
  for (int tl = w; tl < 11; tl += 4) {
    int t = t0 + tl;
    if (t < nterm && c0 + tl * 6 < ncols) {
      float s = ab[t];
#pragma unroll
      for (int h = 0; h < HID; ++h) s += tile[tl * 6 + h][lane] * aw[t * HID + h];
      out[(size_t)(b0 + lane) * OUTW + auxoff + t] = tanhf(s) * av[t] + ac[t];
    }
  }
}

// ---- layer 1: z1T from normalized z0T children + raw dg mid; fused stats ----
__global__ void layer1_zT(const float* __restrict__ C, const float* __restrict__ ss0,
                          const float* __restrict__ W1, const float* __restrict__ b1,
                          float* __restrict__ z1T, float* __restrict__ st) {
  int lane = threadIdx.x & 63, tg = threadIdx.x >> 6;
  int t = blockIdx.x * 4 + tg;
  if (t >= T1N) return;
  int b = blockIdx.y * 64 + lane;
  const float* z0T = C;
  const float* dgm = C + (size_t)3000 * BATCH;
  float x[90];
#pragma unroll
  for (int j = 0; j < 60; ++j) {
    int c = t * 60 + j;
    x[j] = z0T[(size_t)c * BATCH + b] * ss0[2 * c] + ss0[2 * c + 1];
  }
#pragma unroll
  for (int g = 0; g < GPT; ++g)
    x[60 + g] = dgm[(size_t)(t * GPT + g) * BATCH + b];
#pragma unroll
  for (int h = 0; h < HID; ++h) {
    int c = t * HID + h;
    const float* w = W1 + c * 90;
    float s = b1[c];
#pragma unroll
    for (int i = 0; i < 90; ++i) s += x[i] * w[i];
    float z = tanhf(s);
    z1T[(size_t)c * BATCH + b] = z;
    float s1 = z, s2 = z * z;
#pragma unroll
    for (int off = 32; off > 0; off >>= 1) {
      s1 += __shfl_down(s1, off);
      s2 += __shfl_down(s2, off);
    }
    if (lane == 0) {
      atomicAdd(&st[2 * c], s1);
      atomicAdd(&st[2 * c + 1], s2);
    }
  }
}

// ---- root ----
__global__ void root_zT(const float* __restrict__ C, const float* __restrict__ z1T,
                        const float* __restrict__ ss1, const float* __restrict__ W2,
                        const float* __restrict__ b2, float* __restrict__ z2T,
                        float* __restrict__ st) {
  int b = blockIdx.x * 256 + threadIdx.x;
  int lane = threadIdx.x & 63;
  const float* dgr = C + (size_t)4500 * BATCH;
  float s[HID];
#pragma unroll
  for (int h = 0; h < HID; ++h) s[h] = b2[h];
  for (int c = 0; c < 300; ++c) {
    float n = z1T[(size_t)c * BATCH + b] * ss1[2 * c] + ss1[2 * c + 1];
#pragma unroll
    for (int h = 0; h < HID; ++h) s[h] += n * W2[h * 330 + c];
  }
#pragma unroll
  for (int g = 0; g < GPT; ++g) {
    float d = dgr[(size_t)g * BATCH + b];
#pragma unroll
    for (int h = 0; h < HID; ++h) s[h] += d * W2[h * 330 + 300 + g];
  }
#pragma unroll
  for (int h = 0; h < HID; ++h) {
    float z = tanhf(s[h]);
    z2T[(size_t)h * BATCH + b] = z;
    float s1 = z, s2 = z * z;
#pragma unroll
    for (int off = 32; off > 0; off >>= 1) {
      s1 += __shfl_down(s1, off);
      s2 += __shfl_down(s2, off);
    }
    if (lane == 0) {
      atomicAdd(&st[2 * h], s1);
      atomicAdd(&st[2 * h + 1], s2);
    }
  }
}

__global__ void root_emit(const float* __restrict__ z2T, const float* __restrict__ ss2,
                          const float* __restrict__ aw2, const float* __restrict__ ab2,
                          const float* __restrict__ av2, const float* __restrict__ ac2,
                          float* __restrict__ out) {
  int b = blockIdx.x * 256 + threadIdx.x;
  float s = ab2[0];
#pragma unroll
  for (int h = 0; h < HID; ++h) {
    float n = z2T[(size_t)h * BATCH + b] * ss2[2 * h] + ss2[2 * h + 1];
    out[(size_t)b * OUTW + 3851 + h] = n;
    s += n * aw2[h];
  }
  out[(size_t)b * OUTW + 550] = tanhf(s) * av2[0] + ac2[0];
}

extern "C" void kernel_launch(void* const* d_in, const int* in_sizes, int n_in,
                              void* d_out, int out_size, void* d_ws, size_t ws_size,
                              hipStream_t stream) {
  (void)in_sizes; (void)n_in; (void)out_size; (void)ws_size;
  const float* cell = (const float*)d_in[0];
  const float* Wdg  = (const float*)d_in[1];
  const float* bdg  = (const float*)d_in[2];
  const float* W0   = (const float*)d_in[3];
  const float* b0   = (const float*)d_in[4];
  const float* gam0 = (const float*)d_in[5];
  const float* bet0 = (const float*)d_in[6];
  const float* aw0  = (const float*)d_in[7];
  const float* ab0  = (const float*)d_in[8];
  const float* av0  = (const float*)d_in[9];
  const float* ac0  = (const float*)d_in[10];
  const float* W1   = (const float*)d_in[11];
  const float* b1   = (const float*)d_in[12];
  const float* gam1 = (const float*)d_in[13];
  const float* bet1 = (const float*)d_in[14];
  const float* aw1  = (const float*)d_in[15];
  const float* ab1  = (const float*)d_in[16];
  const float* av1  = (const float*)d_in[17];
  const float* ac1  = (const float*)d_in[18];
  const float* W2   = (const float*)d_in[19];
  const float* b2   = (const float*)d_in[20];
  const float* gam2 = (const float*)d_in[21];
  const float* bet2 = (const float*)d_in[22];
  const float* aw2  = (const float*)d_in[23];
  const float* ab2  = (const float*)d_in[24];
  const float* av2  = (const float*)d_in[25];
  const float* ac2  = (const float*)d_in[26];
  float* out = (float*)d_out;

  char* ws = (char*)d_ws;
  unsigned short* cellb = (unsigned short*)(ws);               // 24,641,536
  unsigned short* abuf  = (unsigned short*)(ws + 24641536);    // 27,721,728
  float*          C     = (float*)(ws + 52363264);             // 75,497,472
  float*          z1T   = (float*)(ws + 127860736);            // 4,915,200
  float*          z2T   = (float*)(ws + 132775936);            // 98,304
  float*          st    = (float*)(ws + 132874240);            // 26,448 (pad 32768)
  float*          ssb   = (float*)(ws + 132907008);            // 26,448 (pad 32768)
  float*          bias  = (float*)(ws + 132939776);            // 18,432
  float* st0 = st,  *st1 = st + 2 * 3000,  *st2 = st + 2 * 3300;
  float* ss0 = ssb, *ss1 = ssb + 2 * 3000, *ss2 = ssb + 2 * 3300;

  static int s_attr = 0;
  if (!s_attr) {
    hipFuncSetAttribute(reinterpret_cast<const void*>(gemm_fused),
                        hipFuncAttributeMaxDynamicSharedMemorySize, 73728);
    s_attr = 1;
  }

  hipMemsetAsync(st, 0, 32768, stream);   // layer0/layer1/root stat accumulators
  prep<<<8396, 256, 0, stream>>>(cell, Wdg, bdg, W0, b0,
                                 (ushort8*)cellb, (ushort8*)abuf, bias);
  v0_build<<<dim3(12, T0N), 256, 0, stream>>>(Wdg, W0, abuf);

  gemm_fused<<<576, 512, 73728, stream>>>(abuf, cellb, bias, C, st0);

  bnfin<<<12, 256, 0, stream>>>(st0, gam0, bet0, ss0, 3000);
  norm_emit_aux<<<dim3(46, 64), 256, 0, stream>>>(C, ss0, aw0, ab0, av0, ac0,
                                                  out, 3000, 551, 0, 500);

  layer1_zT<<<dim3(13, 64), 256, 0, stream>>>(C, ss0, W1, b1, z1T, st1);
  bnfin<<<2, 256, 0, stream>>>(st1, gam1, bet1, ss1, 300);
  norm_emit_aux<<<dim3(5, 64), 256, 0, stream>>>(z1T, ss1, aw1, ab1, av1, ac1,
                                                 out, 300, 3551, 500, 50);

  root_zT<<<16, 256, 0, stream>>>(C, z1T, ss1, W2, b2, z2T, st2);
  bnfin<<<1, 256, 0, stream>>>(st2, gam2, bet2, ss2, 6);
  root_emit<<<16, 256, 0, stream>>>(z2T, ss2, aw2, ab2, av2, ac2, out);
}